// Round 13
// baseline (114.635 us; speedup 1.0000x reference)
//
#include <hip/hip_runtime.h>
#include <hip/hip_bf16.h>
#include <cmath>

// ---------------------------------------------------------------------------
// DistanceAwareSelfAttentionHead — bf16 MFMA, round 13.
//   - PV split-K NZ=8 (1024 blocks = 4/CU; R4/R12 occupancy lesson), bf16
//     partials alias dead Ah (exactly 32MB), ordered reduce.
//   - Everything else identical to R12 (111.0us): fused dots in proj,
//     scatter folded into S-GEMM launch, f16 scaled logits, fused
//     softmax+coeff, 6 launches.
//   Ledger: no atomics for split-K bulk (R6); no device-scope fences in hot
//   kernels (R7); >=2 (prefer ~4) blocks/CU for the 2-phase GEMM (R4/R13);
//   reductions register-blocked/vectorized (R9); <=32MB inter-kernel traffic
//   is L3-absorbed (R10); 128^2 tile optimal for this structure.
// ---------------------------------------------------------------------------

typedef short bf16x8 __attribute__((ext_vector_type(8)));
typedef float f32x4  __attribute__((ext_vector_type(4)));
typedef unsigned short ushort_t;
typedef unsigned short ushort8v __attribute__((ext_vector_type(8)));

constexpr int BUCKET = 64;

__device__ __forceinline__ ushort_t f2bf(float f) {
    union { float f; unsigned u; } v; v.f = f;
    unsigned u = v.u;
    u += 0x7FFFu + ((u >> 16) & 1u);   // RNE
    return (ushort_t)(u >> 16);
}
__device__ __forceinline__ float bf2f(ushort_t h) {
    union { unsigned u; float f; } v; v.u = ((unsigned)h) << 16;
    return v.f;
}
__device__ __forceinline__ ushort_t f2h(float f) {
    union { _Float16 h; ushort_t u; } v; v.h = (_Float16)f; return v.u;
}
__device__ __forceinline__ float h2f(ushort_t u) {
    union { ushort_t u; _Float16 h; } v; v.u = u; return (float)v.h;
}
__device__ __forceinline__ void gload_lds16(const void* g, void* l) {
    __builtin_amdgcn_global_load_lds(
        (const __attribute__((address_space(1))) void*)g,
        (__attribute__((address_space(3))) void*)l, 16, 0, 0);
}
__device__ __forceinline__ float red16(float v) {
    v += __shfl_down(v, 8, 16);
    v += __shfl_down(v, 4, 16);
    v += __shfl_down(v, 2, 16);
    v += __shfl_down(v, 1, 16);
    return v;
}

// ---------------------------------------------------------------------------
// 128x128x(BK=32) NT GEMM core
// ---------------------------------------------------------------------------
__device__ __forceinline__ void gemm_core(
    const ushort_t* __restrict__ A, const ushort_t* __restrict__ B,
    int lda, int ldb, int Ksz, size_t kbase, int bm, int bn,
    ushort_t* As, ushort_t* Bs, f32x4 (&acc)[4][4])
{
    constexpr int BK = 32;
    const int tid  = threadIdx.x;
    const int lane = tid & 63;
    const int wid  = tid >> 6;
    const int wm = (wid >> 1) * 64;
    const int wn = (wid & 1) * 64;

    const int r0 = tid >> 2;
    const int c8 = (tid & 3) * 8;
    const ushort_t* Ag0 = A + (size_t)(bm + r0) * lda + kbase + c8;
    const ushort_t* Bg0 = B + (size_t)(bn + r0) * ldb + kbase + c8;
    const ushort_t* Ag1 = Ag0 + (size_t)64 * lda;
    const ushort_t* Bg1 = Bg0 + (size_t)64 * ldb;
    ushort_t* AsW0 = &As[(wid * 64) * 8];
    ushort_t* AsW1 = &As[(256 + wid * 64) * 8];
    ushort_t* BsW0 = &Bs[(wid * 64) * 8];
    ushort_t* BsW1 = &Bs[(256 + wid * 64) * 8];

    const int fr = lane & 15;
    const int kh = (lane >> 4) * 8;

    for (int k0 = 0; k0 < Ksz; k0 += BK) {
        gload_lds16(Ag0 + k0, AsW0);
        gload_lds16(Ag1 + k0, AsW1);
        gload_lds16(Bg0 + k0, BsW0);
        gload_lds16(Bg1 + k0, BsW1);
        __syncthreads();

        bf16x8 af[4], bfv[4];
        #pragma unroll
        for (int i = 0; i < 4; ++i) {
            af[i]  = *(const bf16x8*)&As[(wm + i * 16 + fr) * 32 + kh];
            bfv[i] = *(const bf16x8*)&Bs[(wn + i * 16 + fr) * 32 + kh];
        }
        #pragma unroll
        for (int i = 0; i < 4; ++i)
            #pragma unroll
            for (int j = 0; j < 4; ++j)
                acc[i][j] = __builtin_amdgcn_mfma_f32_16x16x32_bf16(
                    af[i], bfv[j], acc[i][j], 0, 0, 0);
        __syncthreads();
    }
}

__device__ __forceinline__ int swizzle_n(int bid, int nwg)
{
    if ((nwg & 7) == 0) {
        const int cpx = nwg >> 3;
        bid = (bid & 7) * cpx + (bid >> 3);
    }
    return bid;
}

// ---------------------------------------------------------------------------
// proj_gemm: both projections (256 blocks) + fused per-node embedding dots.
// ---------------------------------------------------------------------------
__global__ __launch_bounds__(256) void proj_gemm(
    const ushort_t* __restrict__ xb, const ushort_t* __restrict__ Wqkt,
    const ushort_t* __restrict__ Wvt, ushort_t* __restrict__ qkb,
    ushort_t* __restrict__ vTb,
    const float* __restrict__ Ek, const float* __restrict__ Eq,
    float* __restrict__ qk0, float* __restrict__ qk1,
    float* __restrict__ kq0, float* __restrict__ kq1,
    int FEAT, int HID, int N)
{
    __shared__ ushort_t As[128 * 32];
    __shared__ ushort_t Bs[128 * 32];
    const int b = blockIdx.x;
    const ushort_t* A; const ushort_t* B; ushort_t* C;
    int bm, bn, ldc;
    if (b < 128) {
        const int gx = (2 * HID) / 128;              // 4
        bm = (b / gx) * 128; bn = (b % gx) * 128;
        A = xb; B = Wqkt; C = qkb; ldc = 2 * HID;
    } else {
        const int b2 = b - 128;
        const int gx = N / 128;                      // 32
        bm = (b2 / gx) * 128; bn = (b2 % gx) * 128;
        A = Wvt; B = xb; C = vTb; ldc = N;
    }
    f32x4 acc[4][4] = {};
    gemm_core(A, B, FEAT, FEAT, FEAT, 0, bm, bn, As, Bs, acc);

    const int lane = threadIdx.x & 63;
    const int wid  = threadIdx.x >> 6;
    const int wm = (wid >> 1) * 64, wn = (wid & 1) * 64;
    const int cr = (lane >> 4) * 4, cc = lane & 15;
    #pragma unroll
    for (int i = 0; i < 4; ++i)
        #pragma unroll
        for (int j = 0; j < 4; ++j) {
            const int col = bn + wn + j * 16 + cc;
            const int rowb = bm + wm + i * 16 + cr;
            #pragma unroll
            for (int jj = 0; jj < 4; ++jj)
                C[(size_t)(rowb + jj) * ldc + col] = f2bf(acc[i][j][jj]);
        }

    // fused embedding dots (qk-half only)
    if (b < 128) {
        const bool isQ = (bn < 2 * HID / 2);
        const float* W = isQ ? Ek : Eq;               // [2][HID]
        float* d0 = isQ ? qk0 : kq0;
        float* d1 = isQ ? qk1 : kq1;
        const int hbase = bn - (isQ ? 0 : HID);
        float w0[4], w1[4];
        #pragma unroll
        for (int j = 0; j < 4; ++j) {
            const int h = hbase + wn + j * 16 + cc;
            w0[j] = W[h];
            w1[j] = W[HID + h];
        }
        #pragma unroll
        for (int i = 0; i < 4; ++i)
            #pragma unroll
            for (int jj = 0; jj < 4; ++jj) {
                float s0 = 0.f, s1 = 0.f;
                #pragma unroll
                for (int j = 0; j < 4; ++j) {
                    const float v = acc[i][j][jj];
                    s0 += v * w0[j];
                    s1 += v * w1[j];
                }
                s0 = red16(s0);
                s1 = red16(s1);
                if ((lane & 15) == 0) {
                    const int row = bm + wm + i * 16 + cr + jj;
                    atomicAdd(&d0[row], s0);
                    atomicAdd(&d1[row], s1);
                }
            }
    }
}

// ---------------------------------------------------------------------------
// S GEMM (f16 scaled logits) + folded edge scatter (spare blocks).
// ---------------------------------------------------------------------------
__global__ __launch_bounds__(256) void sgemm_scatter(
    const ushort_t* __restrict__ qkb, ushort_t* __restrict__ Ah,
    const int* __restrict__ ei, const float* __restrict__ attr,
    const float* __restrict__ qk0, const float* __restrict__ qk1,
    const float* __restrict__ kq0, const float* __restrict__ kq1,
    int* __restrict__ rowcnt, int4* __restrict__ ebuf, int4* __restrict__ oflow,
    int N, int HID, int E, int gemmBlocks, float alpha, float scale,
    const float* __restrict__ ibp, const float* __restrict__ imp)
{
    __shared__ ushort_t As[128 * 32];
    __shared__ ushort_t Bs[128 * 32];
    const int b = blockIdx.x;
    if (b >= gemmBlocks) {            // ---- scatter blocks ----
        const int e = (b - gemmBlocks) * 256 + threadIdx.x;
        if (e >= E) return;
        const int src = ei[e];
        const int dst = ei[E + e];
        const float s = 1.f / (1.f + __expf(-(attr[e] - ibp[0]) * imp[0]));
        const float bias = (s * qk0[src] + (1.f - s) * qk1[src]
                          + s * kq0[dst] + (1.f - s) * kq1[dst]) * scale;
        const int pos = atomicAdd(&rowcnt[src], 1);
        if (pos < BUCKET) {
            int4 rec; rec.x = dst; rec.y = __float_as_int(bias);
            rec.z = __float_as_int(s); rec.w = 0;
            ebuf[(size_t)src * BUCKET + pos] = rec;
        } else {
            const int oi = atomicAdd(&rowcnt[N], 1);
            int4 rec; rec.x = src; rec.y = dst;
            rec.z = __float_as_int(bias); rec.w = __float_as_int(s);
            oflow[oi] = rec;
        }
        return;
    }
    // ---- GEMM blocks: Ah = alpha * q k^T (f16) ----
    const int gx = N / 128;
    const int bid = swizzle_n(b, gemmBlocks);
    const int bm = (bid / gx) * 128;
    const int bn = (bid % gx) * 128;
    f32x4 acc[4][4] = {};
    gemm_core(qkb, qkb + HID, 2 * HID, 2 * HID, HID, 0, bm, bn, As, Bs, acc);

    const int lane = threadIdx.x & 63;
    const int wid  = threadIdx.x >> 6;
    const int wm = (wid >> 1) * 64, wn = (wid & 1) * 64;
    const int cr = (lane >> 4) * 4, cc = lane & 15;
    #pragma unroll
    for (int i = 0; i < 4; ++i)
        #pragma unroll
        for (int j = 0; j < 4; ++j) {
            const int col = bn + wn + j * 16 + cc;
            const int rowb = bm + wm + i * 16 + cr;
            #pragma unroll
            for (int jj = 0; jj < 4; ++jj)
                Ah[(size_t)(rowb + jj) * N + col] = f2h(alpha * acc[i][j][jj]);
        }
}

// ---------------------------------------------------------------------------
// PV split-K: parts[z][m][f] (bf16). NZ=8 -> 1024 blocks = 4/CU.
// ---------------------------------------------------------------------------
__global__ __launch_bounds__(256) void pv_gemm_splitk(
    const ushort_t* __restrict__ P, const ushort_t* __restrict__ vT,
    ushort_t* __restrict__ parts, int N, int FEAT, int Kchunk)
{
    __shared__ ushort_t As[128 * 32];
    __shared__ ushort_t Bs[128 * 32];
    const int gx = gridDim.x;
    const int bid = swizzle_n(blockIdx.y * gx + blockIdx.x, gx * gridDim.y);
    const int bm = (bid / gx) * 128;
    const int bn = (bid % gx) * 128;

    f32x4 acc[4][4] = {};
    gemm_core(P, vT, N, N, Kchunk, (size_t)blockIdx.z * Kchunk, bm, bn, As, Bs, acc);

    const int tid = threadIdx.x;
    const int lane = tid & 63;
    const int wid  = tid >> 6;
    const int wm = (wid >> 1) * 64, wn = (wid & 1) * 64;
    const int cr = (lane >> 4) * 4, cc = lane & 15;
    ushort_t* myPart = parts + (size_t)blockIdx.z * N * FEAT;
    #pragma unroll
    for (int i = 0; i < 4; ++i)
        #pragma unroll
        for (int j = 0; j < 4; ++j) {
            const int col = bn + wn + j * 16 + cc;
            const int rowb = bm + wm + i * 16 + cr;
            #pragma unroll
            for (int jj = 0; jj < 4; ++jj)
                myPart[(size_t)(rowb + jj) * FEAT + col] = f2bf(acc[i][j][jj]);
        }
}

// out = sum_z parts[z] (fixed z order) + c0[i]*Ev0 + c1[i]*Ev1
__global__ void reduce_add_rv_kernel(
    const ushort_t* __restrict__ parts, float* __restrict__ out,
    const float* __restrict__ c0, const float* __restrict__ c1,
    const float* __restrict__ Ev, int FEAT, size_t zstride, int nz)
{
    const int i8 = blockIdx.x * 256 + threadIdx.x;
    const int F8 = FEAT / 8;
    const int node = i8 / F8;
    const int f0 = (i8 % F8) * 8;
    float s[8] = {};
    for (int z = 0; z < nz; ++z) {
        const ushort8v p = *(const ushort8v*)(parts + (size_t)z * zstride + (size_t)i8 * 8);
        #pragma unroll
        for (int j = 0; j < 8; ++j) s[j] += bf2f(p[j]);
    }
    const float a0 = c0[node], a1 = c1[node];
    float4 o0, o1;
    const float4 e00 = *(const float4*)(Ev + f0);
    const float4 e01 = *(const float4*)(Ev + f0 + 4);
    const float4 e10 = *(const float4*)(Ev + FEAT + f0);
    const float4 e11 = *(const float4*)(Ev + FEAT + f0 + 4);
    o0.x = s[0] + a0 * e00.x + a1 * e10.x;
    o0.y = s[1] + a0 * e00.y + a1 * e10.y;
    o0.z = s[2] + a0 * e00.z + a1 * e10.z;
    o0.w = s[3] + a0 * e00.w + a1 * e10.w;
    o1.x = s[4] + a0 * e01.x + a1 * e11.x;
    o1.y = s[5] + a0 * e01.y + a1 * e11.y;
    o1.z = s[6] + a0 * e01.z + a1 * e11.z;
    o1.w = s[7] + a0 * e01.w + a1 * e11.w;
    float* op = out + (size_t)node * FEAT + f0;
    *(float4*)op = o0;
    *(float4*)(op + 4) = o1;
}

// ---------------------------------------------------------------------------
// prep: xb = bf16(x); tiled W transposes; zero qk0..kq1 (4N) + rowcnt[N+1].
__global__ __launch_bounds__(256) void prep_kernel(
    const float* __restrict__ x, const float* __restrict__ Wq,
    const float* __restrict__ Wk, const float* __restrict__ Wv,
    ushort_t* __restrict__ xb, ushort_t* __restrict__ Wqkt,
    ushort_t* __restrict__ Wvt, float* __restrict__ dots4,
    int* __restrict__ rowcnt, int N, int FEAT, int HID)
{
    const int b = blockIdx.x;
    const int tid = threadIdx.x;
    const int xBlocks = (N * FEAT / 8) / 256;              // 1024
    const int qkTiles = (FEAT / 32) * (HID / 32);          // 128
    const int vTiles  = (FEAT / 32) * (FEAT / 32);         // 256
    const int zBase = xBlocks + 2 * qkTiles + vTiles;      // 1536

    if (b >= zBase) {                                      // zero dots + rowcnt
        const int i = (b - zBase) * 256 + tid;
        if (i < 4 * N) dots4[i] = 0.f;
        else if (i <= 5 * N) rowcnt[i - 4 * N] = 0;        // rowcnt[0..N]
        return;
    }
    if (b < xBlocks) {
        const int i = b * 256 + tid;
        const float4 a = ((const float4*)x)[2 * i];
        const float4 c = ((const float4*)x)[2 * i + 1];
        ushort8v o;
        o[0] = f2bf(a.x); o[1] = f2bf(a.y); o[2] = f2bf(a.z); o[3] = f2bf(a.w);
        o[4] = f2bf(c.x); o[5] = f2bf(c.y); o[6] = f2bf(c.z); o[7] = f2bf(c.w);
        ((ushort8v*)xb)[i] = o;
        return;
    }

    __shared__ float tile[32][33];
    int t = b - xBlocks;
    const float* src; ushort_t* dst; int I, O;
    if (t < qkTiles)            { src = Wq; dst = Wqkt;                       I = FEAT; O = HID; }
    else if (t < 2 * qkTiles)   { src = Wk; dst = Wqkt + (size_t)HID * FEAT;  I = FEAT; O = HID; t -= qkTiles; }
    else                        { src = Wv; dst = Wvt;                        I = FEAT; O = FEAT; t -= 2 * qkTiles; }
    const int ot = O / 32;
    const int r0 = (t / ot) * 32;
    const int c0 = (t % ot) * 32;
    const int lr = tid >> 5;
    const int lc = tid & 31;
    #pragma unroll
    for (int rr = 0; rr < 32; rr += 8)
        tile[lr + rr][lc] = src[(size_t)(r0 + lr + rr) * O + c0 + lc];
    __syncthreads();
    #pragma unroll
    for (int rr = 0; rr < 32; rr += 8)
        dst[(size_t)(c0 + lr + rr) * I + r0 + lc] = f2bf(tile[lc][lr + rr]);
}

// row softmax + fused edge coefficients
__global__ __launch_bounds__(256) void softmax_rows_bf16(
    const ushort_t* __restrict__ Ah, const int* __restrict__ rowcnt,
    const int4* __restrict__ ebuf, const int4* __restrict__ oflow,
    ushort_t* __restrict__ P, float* __restrict__ c0, float* __restrict__ c1,
    int N)
{
    __shared__ float lbias[4096];      // bias scatter, then reused as P row
    __shared__ float red[4];
    __shared__ float csum[2];
    const int r = blockIdx.x;
    const ushort_t* a = Ah + (size_t)r * N;
    ushort_t* p = P + (size_t)r * N;
    const int t = threadIdx.x;

    #pragma unroll
    for (int u = 0; u < 4; ++u)
        *(float4*)&lbias[(u * 256 + t) * 4] = float4{0.f, 0.f, 0.f, 0.f};
    if (t < 2) csum[t] = 0.f;

    float v[16];
    {
        const ushort8v h0 = ((const ushort8v*)a)[t];
        const ushort8v h1 = ((const ushort8v*)a)[256 + t];
        #pragma unroll
        for (int j = 0; j < 8; ++j) { v[j] = h2f(h0[j]); v[8 + j] = h2f(h1[j]); }
    }
    __syncthreads();

    const int cnt = min(rowcnt[r], BUCKET);
    if (t < cnt) {
        const int4 rec = ebuf[(size_t)r * BUCKET + t];
        atomicAdd(&lbias[rec.x], __int_as_float(rec.y));
    }
    const int ocnt = rowcnt[N];
    for (int j = t; j < ocnt; j += 256) {
        const int4 rec = oflow[j];
        if (rec.x == r) atomicAdd(&lbias[rec.y], __int_as_float(rec.z));
    }
    __syncthreads();

    float mx = -1e30f;
    {
        const int b0 = t * 8, b1 = (256 + t) * 8;
        const float4 l0 = *(const float4*)&lbias[b0];
        const float4 l1 = *(const float4*)&lbias[b0 + 4];
        const float4 l2 = *(const float4*)&lbias[b1];
        const float4 l3 = *(const float4*)&lbias[b1 + 4];
        v[0] += l0.x; v[1] += l0.y; v[2]  += l0.z; v[3]  += l0.w;
        v[4] += l1.x; v[5] += l1.y; v[6]  += l1.z; v[7]  += l1.w;
        v[8] += l2.x; v[9] += l2.y; v[10] += l2.z; v[11] += l2.w;
        v[12] += l3.x; v[13] += l3.y; v[14] += l3.z; v[15] += l3.w;
    }
    #pragma unroll
    for (int j = 0; j < 16; ++j) mx = fmaxf(mx, v[j]);
    #pragma unroll
    for (int off = 32; off > 0; off >>= 1) mx = fmaxf(mx, __shfl_down(mx, off));
    if ((t & 63) == 0) red[t >> 6] = mx;
    __syncthreads();
    const float m = fmaxf(fmaxf(red[0], red[1]), fmaxf(red[2], red[3]));
    __syncthreads();

    float sum = 0.f;
    #pragma unroll
    for (int j = 0; j < 16; ++j) { v[j] = __expf(v[j] - m); sum += v[j]; }
    #pragma unroll
    for (int off = 32; off > 0; off >>= 1) sum += __shfl_down(sum, off);
    if ((t & 63) == 0) red[t >> 6] = sum;
    __syncthreads();
    const float inv = 1.f / (red[0] + red[1] + red[2] + red[3]);

    ushort8v o0, o1;
    {
        const int b0 = t * 8, b1 = (256 + t) * 8;
        #pragma unroll
        for (int j = 0; j < 8; ++j) {
            const float p0 = v[j] * inv;
            const float p1 = v[8 + j] * inv;
            o0[j] = f2bf(p0);
            o1[j] = f2bf(p1);
            lbias[b0 + j] = p0;
            lbias[b1 + j] = p1;
        }
    }
    ((ushort8v*)p)[t] = o0;
    ((ushort8v*)p)[256 + t] = o1;
    __syncthreads();

    if (t < cnt) {
        const int4 rec = ebuf[(size_t)r * BUCKET + t];
        const float s = __int_as_float(rec.z);
        const float pv = lbias[rec.x];
        atomicAdd(&csum[0], pv * s);
        atomicAdd(&csum[1], pv * (1.f - s));
    }
    for (int j = t; j < ocnt; j += 256) {
        const int4 rec = oflow[j];
        if (rec.x == r) {
            const float s = __int_as_float(rec.w);
            const float pv = lbias[rec.y];
            atomicAdd(&csum[0], pv * s);
            atomicAdd(&csum[1], pv * (1.f - s));
        }
    }
    __syncthreads();
    if (t == 0) { c0[r] = csum[0]; c1[r] = csum[1]; }
}

// ---------------------------------------------------------------------------
extern "C" void kernel_launch(void* const* d_in, const int* in_sizes, int n_in,
                              void* d_out, int out_size, void* d_ws, size_t ws_size,
                              hipStream_t stream)
{
    const float* x    = (const float*)d_in[0];
    const int*   ei   = (const int*)d_in[1];
    const float* attr = (const float*)d_in[2];
    const float* Wk   = (const float*)d_in[3];
    const float* Wq   = (const float*)d_in[4];
    const float* Wv   = (const float*)d_in[5];
    const float* Ek   = (const float*)d_in[6];
    const float* Eq   = (const float*)d_in[7];
    const float* Ev   = (const float*)d_in[8];
    const float* ib   = (const float*)d_in[9];
    const float* im   = (const float*)d_in[10];
    float* out = (float*)d_out;

    const int FEAT = (int)lroundf(sqrtf((float)in_sizes[5]));   // 512
    const int HID  = in_sizes[3] / FEAT;                        // 256
    const int N    = in_sizes[0] / FEAT;                        // 4096
    const int E    = in_sizes[2];                               // 131072

    char* w = (char*)d_ws;
    size_t o = 0;
    ushort_t* xb   = (ushort_t*)(w + o); o += (size_t)N * FEAT * 2;
    ushort_t* Wqkt = (ushort_t*)(w + o); o += (size_t)2 * HID * FEAT * 2;
    ushort_t* Wvt  = (ushort_t*)(w + o); o += (size_t)FEAT * FEAT * 2;
    ushort_t* qkb  = (ushort_t*)(w + o); o += (size_t)N * 2 * HID * 2;
    ushort_t* vTb  = (ushort_t*)(w + o); o += (size_t)FEAT * N * 2;
    ushort_t* Ah   = (ushort_t*)(w + o); o += (size_t)N * N * 2;   // f16 logits
    ushort_t* Pb   = (ushort_t*)(w + o); o += (size_t)N * N * 2;   // bf16 probs
    float*    qk0  = (float*)(w + o);    o += (size_t)N * 4;       // dots4 base
    float*    qk1  = (float*)(w + o);    o += (size_t)N * 4;
    float*    kq0  = (float*)(w + o);    o += (size_t)N * 4;
    float*    kq1  = (float*)(w + o);    o += (size_t)N * 4;
    float*    c0   = (float*)(w + o);    o += (size_t)N * 4;
    float*    c1   = (float*)(w + o);    o += (size_t)N * 4;
    int*      rowcnt = (int*)(w + o);    o += (size_t)(N + 8) * 4; // [N]=oflowcnt
    o = (o + 15) & ~(size_t)15;
    int4*     ebuf   = (int4*)(w + o);   o += (size_t)N * BUCKET * 16;  // 4 MB
    int4*     oflow  = (int4*)(w + o);   o += (size_t)E * 16;           // safety cap
    ushort_t* pvpart = Ah;   // logits dead after softmax; 8 x 4MB bf16 = 32MB

    const dim3 blk(256);
    const int NZ = 8;
    const int Kchunk = N / NZ;                                  // 512
    const float scale = 1.f / sqrtf((float)FEAT);

    // 1) prep: x->bf16 + tiled weight transposes + zero dots/rowcnt
    const int xBlocks = (N * FEAT / 8) / 256;                   // 1024
    const int qkTiles = (FEAT / 32) * (HID / 32);               // 128
    const int vTiles  = (FEAT / 32) * (FEAT / 32);              // 256
    const int zBlocks = (5 * N + 1 + 255) / 256;                // 81
    prep_kernel<<<xBlocks + 2 * qkTiles + vTiles + zBlocks, blk, 0, stream>>>(
        x, Wq, Wk, Wv, xb, Wqkt, Wvt, qk0, rowcnt, N, FEAT, HID);

    // 2) projections + fused embedding dots
    proj_gemm<<<256, blk, 0, stream>>>(xb, Wqkt, Wvt, qkb, vTb,
                                       Ek, Eq, qk0, qk1, kq0, kq1,
                                       FEAT, HID, N);

    // 3) S GEMM (f16, scale folded) + folded edge scatter
    const int gemmBlocks = (N / 128) * (N / 128);               // 1024
    const int scatBlocks = (E + 255) / 256;                     // 512
    sgemm_scatter<<<gemmBlocks + scatBlocks, blk, 0, stream>>>(
        qkb, Ah, ei, attr, qk0, qk1, kq0, kq1, rowcnt, ebuf, oflow,
        N, HID, E, gemmBlocks, 2.f * scale, scale, ib, im);

    // 4) P = softmax(Ah + edge bias) -> bf16; fused c0/c1
    softmax_rows_bf16<<<N, blk, 0, stream>>>(Ah, rowcnt, ebuf, oflow, Pb, c0, c1, N);

    // 5) PV split-K NZ=8 (bf16 partials into dead Ah; 1024 blocks = 4/CU)
    pv_gemm_splitk<<<dim3(FEAT / 128, N / 128, NZ), blk, 0, stream>>>(
        Pb, vTb, pvpart, N, FEAT, Kchunk);

    // 6) out = sum_z partials + c0[i]*Ev0 + c1[i]*Ev1
    reduce_add_rv_kernel<<<(N * FEAT / 8) / 256, blk, 0, stream>>>(
        pvpart, out, c0, c1, Ev, FEAT, (size_t)N * FEAT, NZ);
}

// Round 14
// 110.966 us; speedup vs baseline: 1.0331x; 1.0331x over previous
//
#include <hip/hip_runtime.h>
#include <hip/hip_bf16.h>
#include <cmath>

// ---------------------------------------------------------------------------
// DistanceAwareSelfAttentionHead — bf16 MFMA, round 14 (= R12 revert).
//   - PV split-K NZ=4 (512 blocks = 2/CU; measured optimum R12/R13), bf16
//     partials alias dead Ah, ordered reduce kernel.
//   - Fused dots in proj epilogue; scatter folded into S-GEMM launch;
//     f16 scaled logits; fused softmax+coeff. 6 launches.
//   Ledger: no atomics for split-K bulk (R6); no device-scope fences in hot
//   kernels (R7); 2 blocks/CU + minimal partials is the split-K optimum
//   (R4: 1/CU bad; R13: NZ=8 traffic > occupancy gain); reductions
//   register-blocked/vectorized (R9); <=32MB inter-kernel traffic is
//   L3-absorbed (R10); 128^2 tile optimal for this structure.
// ---------------------------------------------------------------------------

typedef short bf16x8 __attribute__((ext_vector_type(8)));
typedef float f32x4  __attribute__((ext_vector_type(4)));
typedef unsigned short ushort_t;
typedef unsigned short ushort8v __attribute__((ext_vector_type(8)));

constexpr int BUCKET = 64;

__device__ __forceinline__ ushort_t f2bf(float f) {
    union { float f; unsigned u; } v; v.f = f;
    unsigned u = v.u;
    u += 0x7FFFu + ((u >> 16) & 1u);   // RNE
    return (ushort_t)(u >> 16);
}
__device__ __forceinline__ float bf2f(ushort_t h) {
    union { unsigned u; float f; } v; v.u = ((unsigned)h) << 16;
    return v.f;
}
__device__ __forceinline__ ushort_t f2h(float f) {
    union { _Float16 h; ushort_t u; } v; v.h = (_Float16)f; return v.u;
}
__device__ __forceinline__ float h2f(ushort_t u) {
    union { ushort_t u; _Float16 h; } v; v.u = u; return (float)v.h;
}
__device__ __forceinline__ void gload_lds16(const void* g, void* l) {
    __builtin_amdgcn_global_load_lds(
        (const __attribute__((address_space(1))) void*)g,
        (__attribute__((address_space(3))) void*)l, 16, 0, 0);
}
__device__ __forceinline__ float red16(float v) {
    v += __shfl_down(v, 8, 16);
    v += __shfl_down(v, 4, 16);
    v += __shfl_down(v, 2, 16);
    v += __shfl_down(v, 1, 16);
    return v;
}

// ---------------------------------------------------------------------------
// 128x128x(BK=32) NT GEMM core
// ---------------------------------------------------------------------------
__device__ __forceinline__ void gemm_core(
    const ushort_t* __restrict__ A, const ushort_t* __restrict__ B,
    int lda, int ldb, int Ksz, size_t kbase, int bm, int bn,
    ushort_t* As, ushort_t* Bs, f32x4 (&acc)[4][4])
{
    constexpr int BK = 32;
    const int tid  = threadIdx.x;
    const int lane = tid & 63;
    const int wid  = tid >> 6;
    const int wm = (wid >> 1) * 64;
    const int wn = (wid & 1) * 64;

    const int r0 = tid >> 2;
    const int c8 = (tid & 3) * 8;
    const ushort_t* Ag0 = A + (size_t)(bm + r0) * lda + kbase + c8;
    const ushort_t* Bg0 = B + (size_t)(bn + r0) * ldb + kbase + c8;
    const ushort_t* Ag1 = Ag0 + (size_t)64 * lda;
    const ushort_t* Bg1 = Bg0 + (size_t)64 * ldb;
    ushort_t* AsW0 = &As[(wid * 64) * 8];
    ushort_t* AsW1 = &As[(256 + wid * 64) * 8];
    ushort_t* BsW0 = &Bs[(wid * 64) * 8];
    ushort_t* BsW1 = &Bs[(256 + wid * 64) * 8];

    const int fr = lane & 15;
    const int kh = (lane >> 4) * 8;

    for (int k0 = 0; k0 < Ksz; k0 += BK) {
        gload_lds16(Ag0 + k0, AsW0);
        gload_lds16(Ag1 + k0, AsW1);
        gload_lds16(Bg0 + k0, BsW0);
        gload_lds16(Bg1 + k0, BsW1);
        __syncthreads();

        bf16x8 af[4], bfv[4];
        #pragma unroll
        for (int i = 0; i < 4; ++i) {
            af[i]  = *(const bf16x8*)&As[(wm + i * 16 + fr) * 32 + kh];
            bfv[i] = *(const bf16x8*)&Bs[(wn + i * 16 + fr) * 32 + kh];
        }
        #pragma unroll
        for (int i = 0; i < 4; ++i)
            #pragma unroll
            for (int j = 0; j < 4; ++j)
                acc[i][j] = __builtin_amdgcn_mfma_f32_16x16x32_bf16(
                    af[i], bfv[j], acc[i][j], 0, 0, 0);
        __syncthreads();
    }
}

__device__ __forceinline__ int swizzle_n(int bid, int nwg)
{
    if ((nwg & 7) == 0) {
        const int cpx = nwg >> 3;
        bid = (bid & 7) * cpx + (bid >> 3);
    }
    return bid;
}

// ---------------------------------------------------------------------------
// proj_gemm: both projections (256 blocks) + fused per-node embedding dots.
// ---------------------------------------------------------------------------
__global__ __launch_bounds__(256) void proj_gemm(
    const ushort_t* __restrict__ xb, const ushort_t* __restrict__ Wqkt,
    const ushort_t* __restrict__ Wvt, ushort_t* __restrict__ qkb,
    ushort_t* __restrict__ vTb,
    const float* __restrict__ Ek, const float* __restrict__ Eq,
    float* __restrict__ qk0, float* __restrict__ qk1,
    float* __restrict__ kq0, float* __restrict__ kq1,
    int FEAT, int HID, int N)
{
    __shared__ ushort_t As[128 * 32];
    __shared__ ushort_t Bs[128 * 32];
    const int b = blockIdx.x;
    const ushort_t* A; const ushort_t* B; ushort_t* C;
    int bm, bn, ldc;
    if (b < 128) {
        const int gx = (2 * HID) / 128;              // 4
        bm = (b / gx) * 128; bn = (b % gx) * 128;
        A = xb; B = Wqkt; C = qkb; ldc = 2 * HID;
    } else {
        const int b2 = b - 128;
        const int gx = N / 128;                      // 32
        bm = (b2 / gx) * 128; bn = (b2 % gx) * 128;
        A = Wvt; B = xb; C = vTb; ldc = N;
    }
    f32x4 acc[4][4] = {};
    gemm_core(A, B, FEAT, FEAT, FEAT, 0, bm, bn, As, Bs, acc);

    const int lane = threadIdx.x & 63;
    const int wid  = threadIdx.x >> 6;
    const int wm = (wid >> 1) * 64, wn = (wid & 1) * 64;
    const int cr = (lane >> 4) * 4, cc = lane & 15;
    #pragma unroll
    for (int i = 0; i < 4; ++i)
        #pragma unroll
        for (int j = 0; j < 4; ++j) {
            const int col = bn + wn + j * 16 + cc;
            const int rowb = bm + wm + i * 16 + cr;
            #pragma unroll
            for (int jj = 0; jj < 4; ++jj)
                C[(size_t)(rowb + jj) * ldc + col] = f2bf(acc[i][j][jj]);
        }

    // fused embedding dots (qk-half only)
    if (b < 128) {
        const bool isQ = (bn < 2 * HID / 2);
        const float* W = isQ ? Ek : Eq;               // [2][HID]
        float* d0 = isQ ? qk0 : kq0;
        float* d1 = isQ ? qk1 : kq1;
        const int hbase = bn - (isQ ? 0 : HID);
        float w0[4], w1[4];
        #pragma unroll
        for (int j = 0; j < 4; ++j) {
            const int h = hbase + wn + j * 16 + cc;
            w0[j] = W[h];
            w1[j] = W[HID + h];
        }
        #pragma unroll
        for (int i = 0; i < 4; ++i)
            #pragma unroll
            for (int jj = 0; jj < 4; ++jj) {
                float s0 = 0.f, s1 = 0.f;
                #pragma unroll
                for (int j = 0; j < 4; ++j) {
                    const float v = acc[i][j][jj];
                    s0 += v * w0[j];
                    s1 += v * w1[j];
                }
                s0 = red16(s0);
                s1 = red16(s1);
                if ((lane & 15) == 0) {
                    const int row = bm + wm + i * 16 + cr + jj;
                    atomicAdd(&d0[row], s0);
                    atomicAdd(&d1[row], s1);
                }
            }
    }
}

// ---------------------------------------------------------------------------
// S GEMM (f16 scaled logits) + folded edge scatter (spare blocks).
// ---------------------------------------------------------------------------
__global__ __launch_bounds__(256) void sgemm_scatter(
    const ushort_t* __restrict__ qkb, ushort_t* __restrict__ Ah,
    const int* __restrict__ ei, const float* __restrict__ attr,
    const float* __restrict__ qk0, const float* __restrict__ qk1,
    const float* __restrict__ kq0, const float* __restrict__ kq1,
    int* __restrict__ rowcnt, int4* __restrict__ ebuf, int4* __restrict__ oflow,
    int N, int HID, int E, int gemmBlocks, float alpha, float scale,
    const float* __restrict__ ibp, const float* __restrict__ imp)
{
    __shared__ ushort_t As[128 * 32];
    __shared__ ushort_t Bs[128 * 32];
    const int b = blockIdx.x;
    if (b >= gemmBlocks) {            // ---- scatter blocks ----
        const int e = (b - gemmBlocks) * 256 + threadIdx.x;
        if (e >= E) return;
        const int src = ei[e];
        const int dst = ei[E + e];
        const float s = 1.f / (1.f + __expf(-(attr[e] - ibp[0]) * imp[0]));
        const float bias = (s * qk0[src] + (1.f - s) * qk1[src]
                          + s * kq0[dst] + (1.f - s) * kq1[dst]) * scale;
        const int pos = atomicAdd(&rowcnt[src], 1);
        if (pos < BUCKET) {
            int4 rec; rec.x = dst; rec.y = __float_as_int(bias);
            rec.z = __float_as_int(s); rec.w = 0;
            ebuf[(size_t)src * BUCKET + pos] = rec;
        } else {
            const int oi = atomicAdd(&rowcnt[N], 1);
            int4 rec; rec.x = src; rec.y = dst;
            rec.z = __float_as_int(bias); rec.w = __float_as_int(s);
            oflow[oi] = rec;
        }
        return;
    }
    // ---- GEMM blocks: Ah = alpha * q k^T (f16) ----
    const int gx = N / 128;
    const int bid = swizzle_n(b, gemmBlocks);
    const int bm = (bid / gx) * 128;
    const int bn = (bid % gx) * 128;
    f32x4 acc[4][4] = {};
    gemm_core(qkb, qkb + HID, 2 * HID, 2 * HID, HID, 0, bm, bn, As, Bs, acc);

    const int lane = threadIdx.x & 63;
    const int wid  = threadIdx.x >> 6;
    const int wm = (wid >> 1) * 64, wn = (wid & 1) * 64;
    const int cr = (lane >> 4) * 4, cc = lane & 15;
    #pragma unroll
    for (int i = 0; i < 4; ++i)
        #pragma unroll
        for (int j = 0; j < 4; ++j) {
            const int col = bn + wn + j * 16 + cc;
            const int rowb = bm + wm + i * 16 + cr;
            #pragma unroll
            for (int jj = 0; jj < 4; ++jj)
                Ah[(size_t)(rowb + jj) * N + col] = f2h(alpha * acc[i][j][jj]);
        }
}

// ---------------------------------------------------------------------------
// PV split-K: parts[z][m][f] (bf16). NZ=4 -> 512 blocks = 2/CU (optimum).
// ---------------------------------------------------------------------------
__global__ __launch_bounds__(256) void pv_gemm_splitk(
    const ushort_t* __restrict__ P, const ushort_t* __restrict__ vT,
    ushort_t* __restrict__ parts, int N, int FEAT, int Kchunk)
{
    __shared__ ushort_t As[128 * 32];
    __shared__ ushort_t Bs[128 * 32];
    const int gx = gridDim.x;
    const int bid = swizzle_n(blockIdx.y * gx + blockIdx.x, gx * gridDim.y);
    const int bm = (bid / gx) * 128;
    const int bn = (bid % gx) * 128;

    f32x4 acc[4][4] = {};
    gemm_core(P, vT, N, N, Kchunk, (size_t)blockIdx.z * Kchunk, bm, bn, As, Bs, acc);

    const int tid = threadIdx.x;
    const int lane = tid & 63;
    const int wid  = tid >> 6;
    const int wm = (wid >> 1) * 64, wn = (wid & 1) * 64;
    const int cr = (lane >> 4) * 4, cc = lane & 15;
    ushort_t* myPart = parts + (size_t)blockIdx.z * N * FEAT;
    #pragma unroll
    for (int i = 0; i < 4; ++i)
        #pragma unroll
        for (int j = 0; j < 4; ++j) {
            const int col = bn + wn + j * 16 + cc;
            const int rowb = bm + wm + i * 16 + cr;
            #pragma unroll
            for (int jj = 0; jj < 4; ++jj)
                myPart[(size_t)(rowb + jj) * FEAT + col] = f2bf(acc[i][j][jj]);
        }
}

// out = sum_z parts[z] (fixed z order) + c0[i]*Ev0 + c1[i]*Ev1
__global__ void reduce_add_rv_kernel(
    const ushort_t* __restrict__ parts, float* __restrict__ out,
    const float* __restrict__ c0, const float* __restrict__ c1,
    const float* __restrict__ Ev, int FEAT, size_t zstride, int nz)
{
    const int i8 = blockIdx.x * 256 + threadIdx.x;
    const int F8 = FEAT / 8;
    const int node = i8 / F8;
    const int f0 = (i8 % F8) * 8;
    float s[8] = {};
    for (int z = 0; z < nz; ++z) {
        const ushort8v p = *(const ushort8v*)(parts + (size_t)z * zstride + (size_t)i8 * 8);
        #pragma unroll
        for (int j = 0; j < 8; ++j) s[j] += bf2f(p[j]);
    }
    const float a0 = c0[node], a1 = c1[node];
    float4 o0, o1;
    const float4 e00 = *(const float4*)(Ev + f0);
    const float4 e01 = *(const float4*)(Ev + f0 + 4);
    const float4 e10 = *(const float4*)(Ev + FEAT + f0);
    const float4 e11 = *(const float4*)(Ev + FEAT + f0 + 4);
    o0.x = s[0] + a0 * e00.x + a1 * e10.x;
    o0.y = s[1] + a0 * e00.y + a1 * e10.y;
    o0.z = s[2] + a0 * e00.z + a1 * e10.z;
    o0.w = s[3] + a0 * e00.w + a1 * e10.w;
    o1.x = s[4] + a0 * e01.x + a1 * e11.x;
    o1.y = s[5] + a0 * e01.y + a1 * e11.y;
    o1.z = s[6] + a0 * e01.z + a1 * e11.z;
    o1.w = s[7] + a0 * e01.w + a1 * e11.w;
    float* op = out + (size_t)node * FEAT + f0;
    *(float4*)op = o0;
    *(float4*)(op + 4) = o1;
}

// ---------------------------------------------------------------------------
// prep: xb = bf16(x); tiled W transposes; zero qk0..kq1 (4N) + rowcnt[N+1].
__global__ __launch_bounds__(256) void prep_kernel(
    const float* __restrict__ x, const float* __restrict__ Wq,
    const float* __restrict__ Wk, const float* __restrict__ Wv,
    ushort_t* __restrict__ xb, ushort_t* __restrict__ Wqkt,
    ushort_t* __restrict__ Wvt, float* __restrict__ dots4,
    int* __restrict__ rowcnt, int N, int FEAT, int HID)
{
    const int b = blockIdx.x;
    const int tid = threadIdx.x;
    const int xBlocks = (N * FEAT / 8) / 256;              // 1024
    const int qkTiles = (FEAT / 32) * (HID / 32);          // 128
    const int vTiles  = (FEAT / 32) * (FEAT / 32);         // 256
    const int zBase = xBlocks + 2 * qkTiles + vTiles;      // 1536

    if (b >= zBase) {                                      // zero dots + rowcnt
        const int i = (b - zBase) * 256 + tid;
        if (i < 4 * N) dots4[i] = 0.f;
        else if (i <= 5 * N) rowcnt[i - 4 * N] = 0;        // rowcnt[0..N]
        return;
    }
    if (b < xBlocks) {
        const int i = b * 256 + tid;
        const float4 a = ((const float4*)x)[2 * i];
        const float4 c = ((const float4*)x)[2 * i + 1];
        ushort8v o;
        o[0] = f2bf(a.x); o[1] = f2bf(a.y); o[2] = f2bf(a.z); o[3] = f2bf(a.w);
        o[4] = f2bf(c.x); o[5] = f2bf(c.y); o[6] = f2bf(c.z); o[7] = f2bf(c.w);
        ((ushort8v*)xb)[i] = o;
        return;
    }

    __shared__ float tile[32][33];
    int t = b - xBlocks;
    const float* src; ushort_t* dst; int I, O;
    if (t < qkTiles)            { src = Wq; dst = Wqkt;                       I = FEAT; O = HID; }
    else if (t < 2 * qkTiles)   { src = Wk; dst = Wqkt + (size_t)HID * FEAT;  I = FEAT; O = HID; t -= qkTiles; }
    else                        { src = Wv; dst = Wvt;                        I = FEAT; O = FEAT; t -= 2 * qkTiles; }
    const int ot = O / 32;
    const int r0 = (t / ot) * 32;
    const int c0 = (t % ot) * 32;
    const int lr = tid >> 5;
    const int lc = tid & 31;
    #pragma unroll
    for (int rr = 0; rr < 32; rr += 8)
        tile[lr + rr][lc] = src[(size_t)(r0 + lr + rr) * O + c0 + lc];
    __syncthreads();
    #pragma unroll
    for (int rr = 0; rr < 32; rr += 8)
        dst[(size_t)(c0 + lr + rr) * I + r0 + lc] = f2bf(tile[lc][lr + rr]);
}

// row softmax + fused edge coefficients
__global__ __launch_bounds__(256) void softmax_rows_bf16(
    const ushort_t* __restrict__ Ah, const int* __restrict__ rowcnt,
    const int4* __restrict__ ebuf, const int4* __restrict__ oflow,
    ushort_t* __restrict__ P, float* __restrict__ c0, float* __restrict__ c1,
    int N)
{
    __shared__ float lbias[4096];      // bias scatter, then reused as P row
    __shared__ float red[4];
    __shared__ float csum[2];
    const int r = blockIdx.x;
    const ushort_t* a = Ah + (size_t)r * N;
    ushort_t* p = P + (size_t)r * N;
    const int t = threadIdx.x;

    #pragma unroll
    for (int u = 0; u < 4; ++u)
        *(float4*)&lbias[(u * 256 + t) * 4] = float4{0.f, 0.f, 0.f, 0.f};
    if (t < 2) csum[t] = 0.f;

    float v[16];
    {
        const ushort8v h0 = ((const ushort8v*)a)[t];
        const ushort8v h1 = ((const ushort8v*)a)[256 + t];
        #pragma unroll
        for (int j = 0; j < 8; ++j) { v[j] = h2f(h0[j]); v[8 + j] = h2f(h1[j]); }
    }
    __syncthreads();

    const int cnt = min(rowcnt[r], BUCKET);
    if (t < cnt) {
        const int4 rec = ebuf[(size_t)r * BUCKET + t];
        atomicAdd(&lbias[rec.x], __int_as_float(rec.y));
    }
    const int ocnt = rowcnt[N];
    for (int j = t; j < ocnt; j += 256) {
        const int4 rec = oflow[j];
        if (rec.x == r) atomicAdd(&lbias[rec.y], __int_as_float(rec.z));
    }
    __syncthreads();

    float mx = -1e30f;
    {
        const int b0 = t * 8, b1 = (256 + t) * 8;
        const float4 l0 = *(const float4*)&lbias[b0];
        const float4 l1 = *(const float4*)&lbias[b0 + 4];
        const float4 l2 = *(const float4*)&lbias[b1];
        const float4 l3 = *(const float4*)&lbias[b1 + 4];
        v[0] += l0.x; v[1] += l0.y; v[2]  += l0.z; v[3]  += l0.w;
        v[4] += l1.x; v[5] += l1.y; v[6]  += l1.z; v[7]  += l1.w;
        v[8] += l2.x; v[9] += l2.y; v[10] += l2.z; v[11] += l2.w;
        v[12] += l3.x; v[13] += l3.y; v[14] += l3.z; v[15] += l3.w;
    }
    #pragma unroll
    for (int j = 0; j < 16; ++j) mx = fmaxf(mx, v[j]);
    #pragma unroll
    for (int off = 32; off > 0; off >>= 1) mx = fmaxf(mx, __shfl_down(mx, off));
    if ((t & 63) == 0) red[t >> 6] = mx;
    __syncthreads();
    const float m = fmaxf(fmaxf(red[0], red[1]), fmaxf(red[2], red[3]));
    __syncthreads();

    float sum = 0.f;
    #pragma unroll
    for (int j = 0; j < 16; ++j) { v[j] = __expf(v[j] - m); sum += v[j]; }
    #pragma unroll
    for (int off = 32; off > 0; off >>= 1) sum += __shfl_down(sum, off);
    if ((t & 63) == 0) red[t >> 6] = sum;
    __syncthreads();
    const float inv = 1.f / (red[0] + red[1] + red[2] + red[3]);

    ushort8v o0, o1;
    {
        const int b0 = t * 8, b1 = (256 + t) * 8;
        #pragma unroll
        for (int j = 0; j < 8; ++j) {
            const float p0 = v[j] * inv;
            const float p1 = v[8 + j] * inv;
            o0[j] = f2bf(p0);
            o1[j] = f2bf(p1);
            lbias[b0 + j] = p0;
            lbias[b1 + j] = p1;
        }
    }
    ((ushort8v*)p)[t] = o0;
    ((ushort8v*)p)[256 + t] = o1;
    __syncthreads();

    if (t < cnt) {
        const int4 rec = ebuf[(size_t)r * BUCKET + t];
        const float s = __int_as_float(rec.z);
        const float pv = lbias[rec.x];
        atomicAdd(&csum[0], pv * s);
        atomicAdd(&csum[1], pv * (1.f - s));
    }
    for (int j = t; j < ocnt; j += 256) {
        const int4 rec = oflow[j];
        if (rec.x == r) {
            const float s = __int_as_float(rec.w);
            const float pv = lbias[rec.y];
            atomicAdd(&csum[0], pv * s);
            atomicAdd(&csum[1], pv * (1.f - s));
        }
    }
    __syncthreads();
    if (t == 0) { c0[r] = csum[0]; c1[r] = csum[1]; }
}

// ---------------------------------------------------------------------------
extern "C" void kernel_launch(void* const* d_in, const int* in_sizes, int n_in,
                              void* d_out, int out_size, void* d_ws, size_t ws_size,
                              hipStream_t stream)
{
    const float* x    = (const float*)d_in[0];
    const int*   ei   = (const int*)d_in[1];
    const float* attr = (const float*)d_in[2];
    const float* Wk   = (const float*)d_in[3];
    const float* Wq   = (const float*)d_in[4];
    const float* Wv   = (const float*)d_in[5];
    const float* Ek   = (const float*)d_in[6];
    const float* Eq   = (const float*)d_in[7];
    const float* Ev   = (const float*)d_in[8];
    const float* ib   = (const float*)d_in[9];
    const float* im   = (const float*)d_in[10];
    float* out = (float*)d_out;

    const int FEAT = (int)lroundf(sqrtf((float)in_sizes[5]));   // 512
    const int HID  = in_sizes[3] / FEAT;                        // 256
    const int N    = in_sizes[0] / FEAT;                        // 4096
    const int E    = in_sizes[2];                               // 131072

    char* w = (char*)d_ws;
    size_t o = 0;
    ushort_t* xb   = (ushort_t*)(w + o); o += (size_t)N * FEAT * 2;
    ushort_t* Wqkt = (ushort_t*)(w + o); o += (size_t)2 * HID * FEAT * 2;
    ushort_t* Wvt  = (ushort_t*)(w + o); o += (size_t)FEAT * FEAT * 2;
    ushort_t* qkb  = (ushort_t*)(w + o); o += (size_t)N * 2 * HID * 2;
    ushort_t* vTb  = (ushort_t*)(w + o); o += (size_t)FEAT * N * 2;
    ushort_t* Ah   = (ushort_t*)(w + o); o += (size_t)N * N * 2;   // f16 logits
    ushort_t* Pb   = (ushort_t*)(w + o); o += (size_t)N * N * 2;   // bf16 probs
    float*    qk0  = (float*)(w + o);    o += (size_t)N * 4;       // dots4 base
    float*    qk1  = (float*)(w + o);    o += (size_t)N * 4;
    float*    kq0  = (float*)(w + o);    o += (size_t)N * 4;
    float*    kq1  = (float*)(w + o);    o += (size_t)N * 4;
    float*    c0   = (float*)(w + o);    o += (size_t)N * 4;
    float*    c1   = (float*)(w + o);    o += (size_t)N * 4;
    int*      rowcnt = (int*)(w + o);    o += (size_t)(N + 8) * 4; // [N]=oflowcnt
    o = (o + 15) & ~(size_t)15;
    int4*     ebuf   = (int4*)(w + o);   o += (size_t)N * BUCKET * 16;  // 4 MB
    int4*     oflow  = (int4*)(w + o);   o += (size_t)E * 16;           // safety cap
    ushort_t* pvpart = Ah;   // logits dead after softmax; 4 x 4MB bf16 fits

    const dim3 blk(256);
    const int NZ = 4;
    const int Kchunk = N / NZ;                                  // 1024
    const float scale = 1.f / sqrtf((float)FEAT);

    // 1) prep: x->bf16 + tiled weight transposes + zero dots/rowcnt
    const int xBlocks = (N * FEAT / 8) / 256;                   // 1024
    const int qkTiles = (FEAT / 32) * (HID / 32);               // 128
    const int vTiles  = (FEAT / 32) * (FEAT / 32);              // 256
    const int zBlocks = (5 * N + 1 + 255) / 256;                // 81
    prep_kernel<<<xBlocks + 2 * qkTiles + vTiles + zBlocks, blk, 0, stream>>>(
        x, Wq, Wk, Wv, xb, Wqkt, Wvt, qk0, rowcnt, N, FEAT, HID);

    // 2) projections + fused embedding dots
    proj_gemm<<<256, blk, 0, stream>>>(xb, Wqkt, Wvt, qkb, vTb,
                                       Ek, Eq, qk0, qk1, kq0, kq1,
                                       FEAT, HID, N);

    // 3) S GEMM (f16, scale folded) + folded edge scatter
    const int gemmBlocks = (N / 128) * (N / 128);               // 1024
    const int scatBlocks = (E + 255) / 256;                     // 512
    sgemm_scatter<<<gemmBlocks + scatBlocks, blk, 0, stream>>>(
        qkb, Ah, ei, attr, qk0, qk1, kq0, kq1, rowcnt, ebuf, oflow,
        N, HID, E, gemmBlocks, 2.f * scale, scale, ib, im);

    // 4) P = softmax(Ah + edge bias) -> bf16; fused c0/c1
    softmax_rows_bf16<<<N, blk, 0, stream>>>(Ah, rowcnt, ebuf, oflow, Pb, c0, c1, N);

    // 5) PV split-K NZ=4 (bf16 partials into dead Ah; 512 blocks = 2/CU)
    pv_gemm_splitk<<<dim3(FEAT / 128, N / 128, NZ), blk, 0, stream>>>(
        Pb, vTb, pvpart, N, FEAT, Kchunk);

    // 6) out = sum_z partials + c0[i]*Ev0 + c1[i]*Ev1
    reduce_add_rv_kernel<<<(N * FEAT / 8) / 256, blk, 0, stream>>>(
        pvpart, out, c0, c1, Ev, FEAT, (size_t)N * FEAT, NZ);
}